// Round 1
// baseline (435.558 us; speedup 1.0000x reference)
//
#include <hip/hip_runtime.h>
#include <math.h>

typedef __attribute__((ext_vector_type(8))) short short8;
typedef __attribute__((ext_vector_type(4))) float f32x4;

#define B_   4
#define N_   1024
#define FTOT 3264
#define FPAD 3328

// workspace offsets (bytes)
#define WS_SS   0
#define WS_CG   256
#define WS_SX   4096
#define WS_ABF  151552
#define WS_PT   8540160
// total ws use: 35,803,136 bytes

__device__ __forceinline__ unsigned short f2bf(float x) {
  union { float f; unsigned u; } v; v.f = x;
  unsigned r = v.u + 0x7FFFu + ((v.u >> 16) & 1u);
  return (unsigned short)(r >> 16);
}

__device__ __forceinline__ void gload16(const void* gp, void* lp) {
  __builtin_amdgcn_global_load_lds((const __attribute__((address_space(1))) unsigned int*)gp,
                                   (__attribute__((address_space(3))) unsigned int*)lp, 16, 0, 0);
}

__device__ __forceinline__ float wave_sum(float v) {
#pragma unroll
  for (int off = 32; off > 0; off >>= 1) v += __shfl_down(v, off, 64);
  return v;
}

// ---------------- CG coefficient machinery ----------------
__device__ double dfact(int n) { double r = 1.0; for (int i = 2; i <= n; ++i) r *= (double)i; return r; }

__device__ float cg_coeff(int l1, int m1, int l2, int m2, int L, int M) {
  if (m1 + m2 != M) return 0.f;
  int dl = l1 - l2; if (dl < 0) dl = -dl;
  if (L < dl || L > l1 + l2) return 0.f;
  double pre = sqrt((double)(2*L+1) * dfact(L+l1-l2) * dfact(L-l1+l2) * dfact(l1+l2-L) / dfact(l1+l2+L+1));
  pre *= sqrt(dfact(L+M)*dfact(L-M)*dfact(l1-m1)*dfact(l1+m1)*dfact(l2-m2)*dfact(l2+m2));
  double s = 0.0;
  for (int k = 0; k <= l1 + l2 - L; ++k) {
    int d1 = l1+l2-L-k, d2 = l1-m1-k, d3 = l2+m2-k, d4 = L-l2+m1+k, d5 = L-l1-m2+k;
    if (d1 < 0 || d2 < 0 || d3 < 0 || d4 < 0 || d5 < 0) continue;
    double t = (k & 1) ? -1.0 : 1.0;
    t /= dfact(k)*dfact(d1)*dfact(d2)*dfact(d3)*dfact(d4)*dfact(d5);
    s += t;
  }
  return (float)(pre * s);
}

// 15 CG tables in (L, frag) order; dense [i][j][k] layout, offsets below.
__device__ const int t_l1[15]  = {0,1,2, 0,1,1,1,2,2, 0,1,1,2,2,2};
__device__ const int t_l2[15]  = {0,1,2, 1,0,1,2,1,2, 2,1,2,0,1,2};
__device__ const int t_L [15]  = {0,0,0, 1,1,1,1,1,1, 2,2,2,2,2,2};
__device__ const int t_off[16] = {0,1,10, 35,44,53,80,125,170, 245,270,315,390,415,490, 615};

// per-L frag decode tables (frag order = reference's (l1,l2) loop order)
__device__ const int d_l1[3][6]  = {{0,1,2,0,0,0},{0,1,1,1,2,2},{0,1,1,2,2,2}};
__device__ const int d_l2[3][6]  = {{0,1,2,0,0,0},{1,0,1,2,1,2},{2,1,2,0,1,2}};
__device__ const int d_off[3][6] = {{0,1,10,0,0,0},{35,44,53,80,125,170},{245,270,315,390,415,490}};
__device__ const int d_rb[3] = {0, 1, 4};   // row base of degree l in the 9-row (m) stack

// K0: zero sumsq accumulators + build CG table (runs every launch; graph-safe)
__global__ void k_init(float* ss, float* cg) {
  int tid = threadIdx.x;
  if (tid < 4) ss[tid] = 0.f;
  if (tid >= 615) return;
  int t = 0;
  while (t < 14 && tid >= t_off[t+1]) ++t;
  int local = tid - t_off[t];
  int l1 = t_l1[t], l2 = t_l2[t], L = t_L[t];
  int nk = 2*L+1, n2 = 2*l2+1;
  int k = local % nk; int rest = local / nk;
  int j = rest % n2;  int i = rest / n2;
  cg[tid] = cg_coeff(l1, i - l1, l2, j - l2, L, k - L);
}

// K1: sx[b,n,r] = sum_j s_l[b,n,j,m]  (r = stacked 9 m-rows)
__global__ __launch_bounds__(256) void k_sx(const float* __restrict__ s0p, const float* __restrict__ s1p,
                                            const float* __restrict__ s2p, float* __restrict__ sx) {
  __shared__ float red[9][256];
  const int bn = blockIdx.x;
  const int tid = threadIdx.x;
  const float* p0 = s0p + (size_t)bn * 1024;
  const float* p1 = s1p + (size_t)bn * 3072;
  const float* p2 = s2p + (size_t)bn * 5120;
  float a0 = 0.f;
  for (int i = tid; i < 1024; i += 256) a0 += p0[i];
  float b0 = 0.f, b1 = 0.f, b2 = 0.f;
  for (int i = tid; i < 3072; i += 768) { b0 += p1[i]; b1 += p1[i+256]; b2 += p1[i+512]; }
  float c0=0.f,c1=0.f,c2=0.f,c3=0.f,c4=0.f;
  for (int i = tid; i < 5120; i += 1280) {
    c0 += p2[i]; c1 += p2[i+256]; c2 += p2[i+512]; c3 += p2[i+768]; c4 += p2[i+1024];
  }
  red[0][tid] = a0;
  const int r3 = tid % 3;              // flat idx % 3 == m  (256 ≡ 1 mod 3)
  red[1 + r3][tid]        = b0;
  red[1 + (r3+1)%3][tid]  = b1;
  red[1 + (r3+2)%3][tid]  = b2;
  const int r5 = tid % 5;              // 256 ≡ 1 mod 5
  red[4 + r5][tid]        = c0;
  red[4 + (r5+1)%5][tid]  = c1;
  red[4 + (r5+2)%5][tid]  = c2;
  red[4 + (r5+3)%5][tid]  = c3;
  red[4 + (r5+4)%5][tid]  = c4;
  __syncthreads();
  for (int s = 128; s > 0; s >>= 1) {
    if (tid < s) {
#pragma unroll
      for (int r = 0; r < 9; ++r) red[r][tid] += red[r][tid + s];
    }
    __syncthreads();
  }
  if (tid < 9) sx[(size_t)bn * 9 + tid] = red[tid][0];
}

// K2: adjacency int32 -> bf16
__global__ __launch_bounds__(256) void k_adj(const int* __restrict__ conn, unsigned short* __restrict__ Abf) {
  const int idx = blockIdx.x * 256 + threadIdx.x;      // 1,048,576 int4s
  int4 c = ((const int4*)conn)[idx];
  ushort4 o;
  o.x = f2bf((float)c.x); o.y = f2bf((float)c.y);
  o.z = f2bf((float)c.z); o.w = f2bf((float)c.w);
  ((ushort4*)Abf)[idx] = o;
}

// K3: CG products -> Pt[b][f][m] (bf16, f padded to 3328 with zeros)
#define VS 584   // 9*64 + 8 pad (breaks 8-way LDS bank aliasing across nodes)
__global__ __launch_bounds__(256) void k_cgp(const float* __restrict__ v0, const float* __restrict__ v1,
                                             const float* __restrict__ v2, const float* __restrict__ sx,
                                             const float* __restrict__ cgt, unsigned short* __restrict__ Pt) {
  __shared__ float vsh[8 * VS];
  __shared__ float sxsh[8 * 17];
  __shared__ float cgsh[615];
  const int b  = blockIdx.x >> 7;
  const int m0 = (blockIdx.x & 127) * 8;
  const int tid = threadIdx.x;
  const size_t nb = (size_t)b * N_ + m0;
  for (int i = tid; i < 512;  i += 256) { int nd = i >> 6,  rc = i & 63;  vsh[nd*VS + rc]       = v0[(nb+nd)*64  + rc]; }
  for (int i = tid; i < 1536; i += 256) { int nd = i / 192, rc = i % 192; vsh[nd*VS + 64 + rc]  = v1[(nb+nd)*192 + rc]; }
  for (int i = tid; i < 2560; i += 256) { int nd = i / 320, rc = i % 320; vsh[nd*VS + 256 + rc] = v2[(nb+nd)*320 + rc]; }
  for (int i = tid; i < 72;   i += 256) { int nd = i / 9,   r  = i % 9;   sxsh[nd*17 + r] = sx[(nb+nd)*9 + r]; }
  for (int i = tid; i < 615;  i += 256) cgsh[i] = cgt[i];
  __syncthreads();
  const int node = tid & 7;
  const int fr   = tid >> 3;   // 0..31
  const float* vbase = &vsh[node * VS];
  const float* sbase = &sxsh[node * 17];
  unsigned short* pout = Pt + (size_t)b * FPAD * 1024 + m0 + node;
  for (int fc = 0; fc < FPAD; fc += 32) {
    const int f = fc + fr;
    float val = 0.f;
    if (f < FTOT) {
      int L, r;
      if (f < 192) { L = 0; r = f; } else if (f < 1344) { L = 1; r = f - 192; } else { L = 2; r = f - 1344; }
      int k, t2;
      if (L == 0) { k = 0; t2 = r; } else { k = r / 384; t2 = r - k * 384; }
      const int frag = t2 >> 6, c = t2 & 63;
      const int l1 = d_l1[L][frag], l2 = d_l2[L][frag];
      const int n1 = 2*l1+1, n2 = 2*l2+1, nk = 2*L+1;
      const float* vr  = vbase + d_rb[l1]*64 + c;
      const float* sr  = sbase + d_rb[l2];
      const float* cgp = &cgsh[d_off[L][frag]] + k;
      for (int i = 0; i < n1; ++i) {
        const float vi = vr[i*64];
        const float* cgi = cgp + i*n2*nk;
        for (int j = 0; j < n2; ++j) val += vi * sr[j] * cgi[j*nk];
      }
    }
    pout[(size_t)f * 1024] = f2bf(val);
  }
}

// K4: mp[b][n][f] = sum_m Pt[f][m]*adj[n][m]; writes UNSCALED into d_out + per-L sumsq atomics.
// m97-style: global_load_lds(16B) staging, 2-barrier K loop, 16 MFMA + 8 ds_read_b128 per K-step.
__global__ __launch_bounds__(256) void k_gemm(const unsigned short* __restrict__ Pt,
                                              const unsigned short* __restrict__ Abf,
                                              float* __restrict__ out, float* __restrict__ ssv) {
  __shared__ unsigned short As[128 * 32];
  __shared__ unsigned short Bs[128 * 32];
  const int b  = blockIdx.z;
  const int f0 = blockIdx.x * 128;        // M dim = f (26 tiles over padded 3328)
  const int n0 = blockIdx.y * 128;        // N dim = n (8 tiles)
  const int tid  = threadIdx.x;
  const int wid  = tid >> 6, lane = tid & 63;
  const int wr   = wid >> 1, wc = wid & 1;
  const int l16  = lane & 15, quad = lane >> 4;

  const unsigned short* pA = Pt  + ((size_t)b * FPAD + f0) * 1024;
  const unsigned short* pB = Abf + ((size_t)b * N_   + n0) * 1024;
  const int r0 = tid >> 2, o0 = (tid & 3) * 8;
  const unsigned short* gA0 = pA + (size_t)r0 * 1024 + o0;
  const unsigned short* gA1 = gA0 + (size_t)64 * 1024;
  const unsigned short* gB0 = pB + (size_t)r0 * 1024 + o0;
  const unsigned short* gB1 = gB0 + (size_t)64 * 1024;
  unsigned short* lA0 = &As[(wid * 64) * 8];
  unsigned short* lA1 = &As[(256 + wid * 64) * 8];
  unsigned short* lB0 = &Bs[(wid * 64) * 8];
  unsigned short* lB1 = &Bs[(256 + wid * 64) * 8];

  f32x4 acc[4][4] = {};

  for (int kb = 0; kb < 1024; kb += 32) {
    gload16(gA0 + kb, lA0);
    gload16(gA1 + kb, lA1);
    gload16(gB0 + kb, lB0);
    gload16(gB1 + kb, lB1);
    __syncthreads();
    short8 af[4], bf[4];
#pragma unroll
    for (int mi = 0; mi < 4; ++mi)
      af[mi] = *(const short8*)&As[(wr*64 + mi*16 + l16)*32 + quad*8];
#pragma unroll
    for (int ni = 0; ni < 4; ++ni)
      bf[ni] = *(const short8*)&Bs[(wc*64 + ni*16 + l16)*32 + quad*8];
#pragma unroll
    for (int mi = 0; mi < 4; ++mi)
#pragma unroll
      for (int ni = 0; ni < 4; ++ni)
        acc[mi][ni] = __builtin_amdgcn_mfma_f32_16x16x32_bf16(af[mi], bf[ni], acc[mi][ni], 0, 0, 0);
    __syncthreads();
  }

  // epilogue: D[row=f_local][col=n_local], row = quad*4+reg, col = lane&15 (m89-verified)
  float ssl0 = 0.f, ssl1 = 0.f, ssl2 = 0.f;
#pragma unroll
  for (int mi = 0; mi < 4; ++mi) {
    const int fbase = f0 + wr*64 + mi*16 + quad*4;   // L boundaries (192,1344,3264) are 16-aligned
    if (fbase >= FTOT) continue;
    float sq = 0.f;
#pragma unroll
    for (int ni = 0; ni < 4; ++ni) {
      const int n = n0 + wc*64 + ni*16 + l16;
      f32x4 v = acc[mi][ni];
      sq += v[0]*v[0] + v[1]*v[1] + v[2]*v[2] + v[3]*v[3];
      *(f32x4*)&out[((size_t)b * N_ + n) * FTOT + fbase] = v;
    }
    if (fbase < 192) ssl0 += sq; else if (fbase < 1344) ssl1 += sq; else ssl2 += sq;
  }
  ssl0 = wave_sum(ssl0); ssl1 = wave_sum(ssl1); ssl2 = wave_sum(ssl2);
  if (lane == 0) {
    if (ssl0 != 0.f) atomicAdd(&ssv[0], ssl0);
    if (ssl1 != 0.f) atomicAdd(&ssv[1], ssl1);
    if (ssl2 != 0.f) atomicAdd(&ssv[2], ssl2);
  }
}

// K5: in-place scale by 64 / ((2L+1)*||mp_L||_F)
__global__ __launch_bounds__(256) void k_scale(float* __restrict__ out, const float* __restrict__ ssv) {
  const int idx = blockIdx.x * 256 + threadIdx.x;   // float4 index
  const int total = B_ * N_ * (FTOT / 4);
  if (idx >= total) return;
  const int f = (idx % (FTOT / 4)) * 4;
  const int L = f < 192 ? 0 : (f < 1344 ? 1 : 2);
  const float sc = 64.f / ((float)(2*L+1) * sqrtf(ssv[L]));
  f32x4* p = (f32x4*)out + idx;
  f32x4 v = *p;
  v *= sc;
  *p = v;
}

extern "C" void kernel_launch(void* const* d_in, const int* in_sizes, int n_in,
                              void* d_out, int out_size, void* d_ws, size_t ws_size,
                              hipStream_t stream) {
  const float* v0 = (const float*)d_in[0];
  const float* v1 = (const float*)d_in[1];
  const float* v2 = (const float*)d_in[2];
  const float* s0 = (const float*)d_in[3];
  const float* s1 = (const float*)d_in[4];
  const float* s2 = (const float*)d_in[5];
  const int* conn = (const int*)d_in[6];
  char* ws = (char*)d_ws;
  float* ss            = (float*)(ws + WS_SS);
  float* cg            = (float*)(ws + WS_CG);
  float* sx            = (float*)(ws + WS_SX);
  unsigned short* Abf  = (unsigned short*)(ws + WS_ABF);
  unsigned short* Pt   = (unsigned short*)(ws + WS_PT);
  float* out = (float*)d_out;

  k_init <<<dim3(1),            dim3(640), 0, stream>>>(ss, cg);
  k_sx   <<<dim3(B_ * N_),      dim3(256), 0, stream>>>(s0, s1, s2, sx);
  k_adj  <<<dim3(4096),         dim3(256), 0, stream>>>(conn, Abf);
  k_cgp  <<<dim3(512),          dim3(256), 0, stream>>>(v0, v1, v2, sx, cg, Pt);
  k_gemm <<<dim3(26, 8, B_),    dim3(256), 0, stream>>>(Pt, Abf, out, ss);
  k_scale<<<dim3(13056),        dim3(256), 0, stream>>>(out, ss);
}

// Round 2
// 350.713 us; speedup vs baseline: 1.2419x; 1.2419x over previous
//
#include <hip/hip_runtime.h>
#include <math.h>

typedef __attribute__((ext_vector_type(8))) short short8;
typedef __attribute__((ext_vector_type(4))) float f32x4;

#define B_   4
#define N_   1024
#define FTOT 3264
#define FPAD 3328

// workspace offsets (bytes)
#define WS_SS   0
#define WS_CG   256
#define WS_SX   4096
#define WS_ABF  151552
#define WS_PT   8540160
// total ws use: 35,803,136 bytes

__device__ __forceinline__ unsigned short f2bf(float x) {
  union { float f; unsigned u; } v; v.f = x;
  unsigned r = v.u + 0x7FFFu + ((v.u >> 16) & 1u);
  return (unsigned short)(r >> 16);
}

__device__ __forceinline__ void gload16(const void* gp, void* lp) {
  __builtin_amdgcn_global_load_lds((const __attribute__((address_space(1))) unsigned int*)gp,
                                   (__attribute__((address_space(3))) unsigned int*)lp, 16, 0, 0);
}

__device__ __forceinline__ float wave_sum(float v) {
#pragma unroll
  for (int off = 32; off > 0; off >>= 1) v += __shfl_down(v, off, 64);
  return v;
}

// ---------------- CG coefficient machinery ----------------
__device__ double dfact(int n) { double r = 1.0; for (int i = 2; i <= n; ++i) r *= (double)i; return r; }

__device__ float cg_coeff(int l1, int m1, int l2, int m2, int L, int M) {
  if (m1 + m2 != M) return 0.f;
  int dl = l1 - l2; if (dl < 0) dl = -dl;
  if (L < dl || L > l1 + l2) return 0.f;
  double pre = sqrt((double)(2*L+1) * dfact(L+l1-l2) * dfact(L-l1+l2) * dfact(l1+l2-L) / dfact(l1+l2+L+1));
  pre *= sqrt(dfact(L+M)*dfact(L-M)*dfact(l1-m1)*dfact(l1+m1)*dfact(l2-m2)*dfact(l2+m2));
  double s = 0.0;
  for (int k = 0; k <= l1 + l2 - L; ++k) {
    int d1 = l1+l2-L-k, d2 = l1-m1-k, d3 = l2+m2-k, d4 = L-l2+m1+k, d5 = L-l1-m2+k;
    if (d1 < 0 || d2 < 0 || d3 < 0 || d4 < 0 || d5 < 0) continue;
    double t = (k & 1) ? -1.0 : 1.0;
    t /= dfact(k)*dfact(d1)*dfact(d2)*dfact(d3)*dfact(d4)*dfact(d5);
    s += t;
  }
  return (float)(pre * s);
}

// 15 CG tables in (L, frag) order; dense [i][j][k] layout, offsets below.
__device__ const int t_l1[15]  = {0,1,2, 0,1,1,1,2,2, 0,1,1,2,2,2};
__device__ const int t_l2[15]  = {0,1,2, 1,0,1,2,1,2, 2,1,2,0,1,2};
__device__ const int t_L [15]  = {0,0,0, 1,1,1,1,1,1, 2,2,2,2,2,2};
__device__ const int t_off[16] = {0,1,10, 35,44,53,80,125,170, 245,270,315,390,415,490, 615};

// per-L frag decode tables (frag order = reference's (l1,l2) loop order)
__device__ const int d_l1[3][6]  = {{0,1,2,0,0,0},{0,1,1,1,2,2},{0,1,1,2,2,2}};
__device__ const int d_l2[3][6]  = {{0,1,2,0,0,0},{1,0,1,2,1,2},{2,1,2,0,1,2}};
__device__ const int d_off[3][6] = {{0,1,10,0,0,0},{35,44,53,80,125,170},{245,270,315,390,415,490}};
__device__ const int d_rb[3] = {0, 1, 4};   // row base of degree l in the 9-row (m) stack

// K0: zero sumsq accumulators + build CG table (runs every launch; graph-safe)
__global__ void k_init(float* ss, float* cg) {
  int tid = threadIdx.x;
  if (tid < 4) ss[tid] = 0.f;
  if (tid >= 615) return;
  int t = 0;
  while (t < 14 && tid >= t_off[t+1]) ++t;
  int local = tid - t_off[t];
  int l1 = t_l1[t], l2 = t_l2[t], L = t_L[t];
  int nk = 2*L+1, n2 = 2*l2+1;
  int k = local % nk; int rest = local / nk;
  int j = rest % n2;  int i = rest / n2;
  cg[tid] = cg_coeff(l1, i - l1, l2, j - l2, L, k - L);
}

// K1: sx[b,n,r] = sum_j s_l[b,n,j,m]  (r = stacked 9 m-rows)
__global__ __launch_bounds__(256) void k_sx(const float* __restrict__ s0p, const float* __restrict__ s1p,
                                            const float* __restrict__ s2p, float* __restrict__ sx) {
  __shared__ float red[9][256];
  const int bn = blockIdx.x;
  const int tid = threadIdx.x;
  const float* p0 = s0p + (size_t)bn * 1024;
  const float* p1 = s1p + (size_t)bn * 3072;
  const float* p2 = s2p + (size_t)bn * 5120;
  float a0 = 0.f;
  for (int i = tid; i < 1024; i += 256) a0 += p0[i];
  float b0 = 0.f, b1 = 0.f, b2 = 0.f;
  for (int i = tid; i < 3072; i += 768) { b0 += p1[i]; b1 += p1[i+256]; b2 += p1[i+512]; }
  float c0=0.f,c1=0.f,c2=0.f,c3=0.f,c4=0.f;
  for (int i = tid; i < 5120; i += 1280) {
    c0 += p2[i]; c1 += p2[i+256]; c2 += p2[i+512]; c3 += p2[i+768]; c4 += p2[i+1024];
  }
  red[0][tid] = a0;
  const int r3 = tid % 3;              // flat idx % 3 == m  (256 ≡ 1 mod 3)
  red[1 + r3][tid]        = b0;
  red[1 + (r3+1)%3][tid]  = b1;
  red[1 + (r3+2)%3][tid]  = b2;
  const int r5 = tid % 5;              // 256 ≡ 1 mod 5
  red[4 + r5][tid]        = c0;
  red[4 + (r5+1)%5][tid]  = c1;
  red[4 + (r5+2)%5][tid]  = c2;
  red[4 + (r5+3)%5][tid]  = c3;
  red[4 + (r5+4)%5][tid]  = c4;
  __syncthreads();
  for (int s = 128; s > 0; s >>= 1) {
    if (tid < s) {
#pragma unroll
      for (int r = 0; r < 9; ++r) red[r][tid] += red[r][tid + s];
    }
    __syncthreads();
  }
  if (tid < 9) sx[(size_t)bn * 9 + tid] = red[tid][0];
}

// K2: adjacency int32 -> bf16
__global__ __launch_bounds__(256) void k_adj(const int* __restrict__ conn, unsigned short* __restrict__ Abf) {
  const int idx = blockIdx.x * 256 + threadIdx.x;      // 1,048,576 int4s
  int4 c = ((const int4*)conn)[idx];
  ushort4 o;
  o.x = f2bf((float)c.x); o.y = f2bf((float)c.y);
  o.z = f2bf((float)c.z); o.w = f2bf((float)c.w);
  ((ushort4*)Abf)[idx] = o;
}

// K3: CG products -> Pt[b][f][m] (bf16, f padded to 3328 with zeros)
// Redesign: lane = m (coalesced 128B stores), LDS holds v transposed per-lane
// contiguous (ds_read_b128), CG weights via scalar loads + register math.
#define VSTRIDE 148   // floats per m-row: 144 data + 4 pad (16B-aligned, odd/4 bank step)
__global__ __launch_bounds__(256) void k_cgp(const float* __restrict__ v0, const float* __restrict__ v1,
                                             const float* __restrict__ v2, const float* __restrict__ sx,
                                             const float* __restrict__ cgt, unsigned short* __restrict__ Pt) {
  __shared__ float vsh[64 * VSTRIDE];   // [m][r*16 + cLocal], r=0..8 stacked rows, 16 c per block
  const int b  = blockIdx.x >> 6;
  const int mt = (blockIdx.x >> 2) & 15;
  const int cq = blockIdx.x & 3;
  const int m0 = mt * 64;
  const int c0 = cq * 16;
  const int tid = threadIdx.x;
  const size_t nb = (size_t)b * N_ + m0;

  // load + transpose v tile: 64 m x 9 rows x 16 c
  for (int e = tid; e < 9216; e += 256) {
    const int m = e / 144, rest = e % 144;
    const int r = rest >> 4, cc = rest & 15;
    float val;
    if (r == 0)      val = v0[(nb + m) * 64 + c0 + cc];
    else if (r < 4)  val = v1[((nb + m) * 3 + (r - 1)) * 64 + c0 + cc];
    else             val = v2[((nb + m) * 5 + (r - 4)) * 64 + c0 + cc];
    vsh[m * VSTRIDE + rest] = val;
  }
  const int lane = tid & 63, wv = tid >> 6;
  float sxr[9];
#pragma unroll
  for (int r = 0; r < 9; ++r) sxr[r] = sx[(nb + lane) * 9 + r];
  __syncthreads();

  unsigned short* pout = Pt + (size_t)b * FPAD * 1024 + m0 + lane;
  const int cw = wv * 4;                       // wave's cLocal base (0,4,8,12)
  const float* vme = &vsh[lane * VSTRIDE + cw];

#pragma unroll
  for (int L = 0; L <= 2; ++L) {
    const int nfrag = (L == 0) ? 3 : 6;
    const int nk = 2 * L + 1;
    const int Lbase = (L == 0) ? 0 : (L == 1 ? 192 : 1344);
    const int Cfrag = nfrag * 64;
#pragma unroll
    for (int frag = 0; frag < nfrag; ++frag) {
      const int l1 = d_l1[L][frag], l2 = d_l2[L][frag];
      const int n1 = 2 * l1 + 1, n2 = 2 * l2 + 1;
      const int rb1 = d_rb[l1], rb2 = d_rb[l2];
      const int cgo = d_off[L][frag];
#pragma unroll
      for (int k = 0; k < nk; ++k) {
        float w[5];
#pragma unroll
        for (int i = 0; i < n1; ++i) {
          float a = 0.f;
#pragma unroll
          for (int j = 0; j < n2; ++j)
            a += sxr[rb2 + j] * cgt[cgo + (i * n2 + j) * nk + k];  // uniform idx -> s_load
          w[i] = a;
        }
        f32x4 val = {0.f, 0.f, 0.f, 0.f};
#pragma unroll
        for (int i = 0; i < n1; ++i) {
          f32x4 vv = *(const f32x4*)(vme + (rb1 + i) * 16);       // ds_read_b128
          val += vv * w[i];
        }
        const int fb = Lbase + k * Cfrag + frag * 64 + c0 + cw;
#pragma unroll
        for (int cc = 0; cc < 4; ++cc)
          pout[(size_t)(fb + cc) * 1024] = f2bf(val[cc]);         // 128B coalesced
      }
    }
  }
  // zero the pad rows f in [3264, 3328)
#pragma unroll
  for (int cc = 0; cc < 4; ++cc)
    pout[(size_t)(FTOT + c0 + cw + cc) * 1024] = 0;
}

// K4: mp[b][n][f] = sum_m Pt[f][m]*adj[n][m]; writes UNSCALED into d_out + per-L sumsq atomics.
// m97-style: global_load_lds(16B) staging, 2-barrier K loop, 16 MFMA + 8 ds_read_b128 per K-step.
__global__ __launch_bounds__(256) void k_gemm(const unsigned short* __restrict__ Pt,
                                              const unsigned short* __restrict__ Abf,
                                              float* __restrict__ out, float* __restrict__ ssv) {
  __shared__ unsigned short As[128 * 32];
  __shared__ unsigned short Bs[128 * 32];
  const int b  = blockIdx.z;
  const int f0 = blockIdx.x * 128;        // M dim = f (26 tiles over padded 3328)
  const int n0 = blockIdx.y * 128;        // N dim = n (8 tiles)
  const int tid  = threadIdx.x;
  const int wid  = tid >> 6, lane = tid & 63;
  const int wr   = wid >> 1, wc = wid & 1;
  const int l16  = lane & 15, quad = lane >> 4;

  const unsigned short* pA = Pt  + ((size_t)b * FPAD + f0) * 1024;
  const unsigned short* pB = Abf + ((size_t)b * N_   + n0) * 1024;
  const int r0 = tid >> 2, o0 = (tid & 3) * 8;
  const unsigned short* gA0 = pA + (size_t)r0 * 1024 + o0;
  const unsigned short* gA1 = gA0 + (size_t)64 * 1024;
  const unsigned short* gB0 = pB + (size_t)r0 * 1024 + o0;
  const unsigned short* gB1 = gB0 + (size_t)64 * 1024;
  unsigned short* lA0 = &As[(wid * 64) * 8];
  unsigned short* lA1 = &As[(256 + wid * 64) * 8];
  unsigned short* lB0 = &Bs[(wid * 64) * 8];
  unsigned short* lB1 = &Bs[(256 + wid * 64) * 8];

  f32x4 acc[4][4] = {};

  for (int kb = 0; kb < 1024; kb += 32) {
    gload16(gA0 + kb, lA0);
    gload16(gA1 + kb, lA1);
    gload16(gB0 + kb, lB0);
    gload16(gB1 + kb, lB1);
    __syncthreads();
    short8 af[4], bf[4];
#pragma unroll
    for (int mi = 0; mi < 4; ++mi)
      af[mi] = *(const short8*)&As[(wr*64 + mi*16 + l16)*32 + quad*8];
#pragma unroll
    for (int ni = 0; ni < 4; ++ni)
      bf[ni] = *(const short8*)&Bs[(wc*64 + ni*16 + l16)*32 + quad*8];
#pragma unroll
    for (int mi = 0; mi < 4; ++mi)
#pragma unroll
      for (int ni = 0; ni < 4; ++ni)
        acc[mi][ni] = __builtin_amdgcn_mfma_f32_16x16x32_bf16(af[mi], bf[ni], acc[mi][ni], 0, 0, 0);
    __syncthreads();
  }

  // epilogue: D[row=f_local][col=n_local], row = quad*4+reg, col = lane&15 (m89-verified)
  float ssl0 = 0.f, ssl1 = 0.f, ssl2 = 0.f;
#pragma unroll
  for (int mi = 0; mi < 4; ++mi) {
    const int fbase = f0 + wr*64 + mi*16 + quad*4;   // L boundaries (192,1344,3264) are 16-aligned
    if (fbase >= FTOT) continue;
    float sq = 0.f;
#pragma unroll
    for (int ni = 0; ni < 4; ++ni) {
      const int n = n0 + wc*64 + ni*16 + l16;
      f32x4 v = acc[mi][ni];
      sq += v[0]*v[0] + v[1]*v[1] + v[2]*v[2] + v[3]*v[3];
      *(f32x4*)&out[((size_t)b * N_ + n) * FTOT + fbase] = v;
    }
    if (fbase < 192) ssl0 += sq; else if (fbase < 1344) ssl1 += sq; else ssl2 += sq;
  }
  ssl0 = wave_sum(ssl0); ssl1 = wave_sum(ssl1); ssl2 = wave_sum(ssl2);
  if (lane == 0) {
    if (ssl0 != 0.f) atomicAdd(&ssv[0], ssl0);
    if (ssl1 != 0.f) atomicAdd(&ssv[1], ssl1);
    if (ssl2 != 0.f) atomicAdd(&ssv[2], ssl2);
  }
}

// K5: in-place scale by 64 / ((2L+1)*||mp_L||_F)
__global__ __launch_bounds__(256) void k_scale(float* __restrict__ out, const float* __restrict__ ssv) {
  const int idx = blockIdx.x * 256 + threadIdx.x;   // float4 index
  const int total = B_ * N_ * (FTOT / 4);
  if (idx >= total) return;
  const int f = (idx % (FTOT / 4)) * 4;
  const int L = f < 192 ? 0 : (f < 1344 ? 1 : 2);
  const float sc = 64.f / ((float)(2*L+1) * sqrtf(ssv[L]));
  f32x4* p = (f32x4*)out + idx;
  f32x4 v = *p;
  v *= sc;
  *p = v;
}

extern "C" void kernel_launch(void* const* d_in, const int* in_sizes, int n_in,
                              void* d_out, int out_size, void* d_ws, size_t ws_size,
                              hipStream_t stream) {
  const float* v0 = (const float*)d_in[0];
  const float* v1 = (const float*)d_in[1];
  const float* v2 = (const float*)d_in[2];
  const float* s0 = (const float*)d_in[3];
  const float* s1 = (const float*)d_in[4];
  const float* s2 = (const float*)d_in[5];
  const int* conn = (const int*)d_in[6];
  char* ws = (char*)d_ws;
  float* ss            = (float*)(ws + WS_SS);
  float* cg            = (float*)(ws + WS_CG);
  float* sx            = (float*)(ws + WS_SX);
  unsigned short* Abf  = (unsigned short*)(ws + WS_ABF);
  unsigned short* Pt   = (unsigned short*)(ws + WS_PT);
  float* out = (float*)d_out;

  k_init <<<dim3(1),            dim3(640), 0, stream>>>(ss, cg);
  k_sx   <<<dim3(B_ * N_),      dim3(256), 0, stream>>>(s0, s1, s2, sx);
  k_adj  <<<dim3(4096),         dim3(256), 0, stream>>>(conn, Abf);
  k_cgp  <<<dim3(256),          dim3(256), 0, stream>>>(v0, v1, v2, sx, cg, Pt);
  k_gemm <<<dim3(26, 8, B_),    dim3(256), 0, stream>>>(Pt, Abf, out, ss);
  k_scale<<<dim3(13056),        dim3(256), 0, stream>>>(out, ss);
}

// Round 3
// 343.079 us; speedup vs baseline: 1.2696x; 1.0223x over previous
//
#include <hip/hip_runtime.h>
#include <math.h>

typedef __attribute__((ext_vector_type(8))) short short8;
typedef __attribute__((ext_vector_type(4))) float f32x4;

#define B_   4
#define N_   1024
#define FTOT 3264
#define FPAD 3328

// workspace offsets (bytes)
#define WS_SS   0
#define WS_CG   256
#define WS_SX   4096
#define WS_ABF  151552
#define WS_PT   8540160
// total ws use: 35,803,136 bytes

__device__ __forceinline__ unsigned short f2bf(float x) {
  union { float f; unsigned u; } v; v.f = x;
  unsigned r = v.u + 0x7FFFu + ((v.u >> 16) & 1u);
  return (unsigned short)(r >> 16);
}

__device__ __forceinline__ void gload16(const void* gp, void* lp) {
  __builtin_amdgcn_global_load_lds((const __attribute__((address_space(1))) unsigned int*)gp,
                                   (__attribute__((address_space(3))) unsigned int*)lp, 16, 0, 0);
}

__device__ __forceinline__ float wave_sum(float v) {
#pragma unroll
  for (int off = 32; off > 0; off >>= 1) v += __shfl_down(v, off, 64);
  return v;
}

// ---------------- CG coefficient machinery ----------------
__device__ double dfact(int n) { double r = 1.0; for (int i = 2; i <= n; ++i) r *= (double)i; return r; }

__device__ float cg_coeff(int l1, int m1, int l2, int m2, int L, int M) {
  if (m1 + m2 != M) return 0.f;
  int dl = l1 - l2; if (dl < 0) dl = -dl;
  if (L < dl || L > l1 + l2) return 0.f;
  double pre = sqrt((double)(2*L+1) * dfact(L+l1-l2) * dfact(L-l1+l2) * dfact(l1+l2-L) / dfact(l1+l2+L+1));
  pre *= sqrt(dfact(L+M)*dfact(L-M)*dfact(l1-m1)*dfact(l1+m1)*dfact(l2-m2)*dfact(l2+m2));
  double s = 0.0;
  for (int k = 0; k <= l1 + l2 - L; ++k) {
    int d1 = l1+l2-L-k, d2 = l1-m1-k, d3 = l2+m2-k, d4 = L-l2+m1+k, d5 = L-l1-m2+k;
    if (d1 < 0 || d2 < 0 || d3 < 0 || d4 < 0 || d5 < 0) continue;
    double t = (k & 1) ? -1.0 : 1.0;
    t /= dfact(k)*dfact(d1)*dfact(d2)*dfact(d3)*dfact(d4)*dfact(d5);
    s += t;
  }
  return (float)(pre * s);
}

// 15 CG tables in (L, frag) order; dense [i][j][k] layout, offsets below.
__device__ const int t_l1[15]  = {0,1,2, 0,1,1,1,2,2, 0,1,1,2,2,2};
__device__ const int t_l2[15]  = {0,1,2, 1,0,1,2,1,2, 2,1,2,0,1,2};
__device__ const int t_L [15]  = {0,0,0, 1,1,1,1,1,1, 2,2,2,2,2,2};
__device__ const int t_off[16] = {0,1,10, 35,44,53,80,125,170, 245,270,315,390,415,490, 615};

// per-L frag decode tables (frag order = reference's (l1,l2) loop order)
__device__ const int d_l1[3][6]  = {{0,1,2,0,0,0},{0,1,1,1,2,2},{0,1,1,2,2,2}};
__device__ const int d_l2[3][6]  = {{0,1,2,0,0,0},{1,0,1,2,1,2},{2,1,2,0,1,2}};
__device__ const int d_off[3][6] = {{0,1,10,0,0,0},{35,44,53,80,125,170},{245,270,315,390,415,490}};
__device__ const int d_rb[3] = {0, 1, 4};   // row base of degree l in the 9-row (m) stack

// K0: zero sumsq accumulators + build CG table (runs every launch; graph-safe)
__global__ void k_init(float* ss, float* cg) {
  int tid = threadIdx.x;
  if (tid < 4) ss[tid] = 0.f;
  if (tid >= 615) return;
  int t = 0;
  while (t < 14 && tid >= t_off[t+1]) ++t;
  int local = tid - t_off[t];
  int l1 = t_l1[t], l2 = t_l2[t], L = t_L[t];
  int nk = 2*L+1, n2 = 2*l2+1;
  int k = local % nk; int rest = local / nk;
  int j = rest % n2;  int i = rest / n2;
  cg[tid] = cg_coeff(l1, i - l1, l2, j - l2, L, k - L);
}

// K1: sx[b,n,r] = sum_j s_l[b,n,j,m]  (r = stacked 9 m-rows)
__global__ __launch_bounds__(256) void k_sx(const float* __restrict__ s0p, const float* __restrict__ s1p,
                                            const float* __restrict__ s2p, float* __restrict__ sx) {
  __shared__ float red[9][256];
  const int bn = blockIdx.x;
  const int tid = threadIdx.x;
  const float* p0 = s0p + (size_t)bn * 1024;
  const float* p1 = s1p + (size_t)bn * 3072;
  const float* p2 = s2p + (size_t)bn * 5120;
  float a0 = 0.f;
  for (int i = tid; i < 1024; i += 256) a0 += p0[i];
  float b0 = 0.f, b1 = 0.f, b2 = 0.f;
  for (int i = tid; i < 3072; i += 768) { b0 += p1[i]; b1 += p1[i+256]; b2 += p1[i+512]; }
  float c0=0.f,c1=0.f,c2=0.f,c3=0.f,c4=0.f;
  for (int i = tid; i < 5120; i += 1280) {
    c0 += p2[i]; c1 += p2[i+256]; c2 += p2[i+512]; c3 += p2[i+768]; c4 += p2[i+1024];
  }
  red[0][tid] = a0;
  const int r3 = tid % 3;              // flat idx % 3 == m  (256 ≡ 1 mod 3)
  red[1 + r3][tid]        = b0;
  red[1 + (r3+1)%3][tid]  = b1;
  red[1 + (r3+2)%3][tid]  = b2;
  const int r5 = tid % 5;              // 256 ≡ 1 mod 5
  red[4 + r5][tid]        = c0;
  red[4 + (r5+1)%5][tid]  = c1;
  red[4 + (r5+2)%5][tid]  = c2;
  red[4 + (r5+3)%5][tid]  = c3;
  red[4 + (r5+4)%5][tid]  = c4;
  __syncthreads();
  for (int s = 128; s > 0; s >>= 1) {
    if (tid < s) {
#pragma unroll
      for (int r = 0; r < 9; ++r) red[r][tid] += red[r][tid + s];
    }
    __syncthreads();
  }
  if (tid < 9) sx[(size_t)bn * 9 + tid] = red[tid][0];
}

// K2: adjacency int32 -> bf16, written in GEMM-tiled layout
// AbT[b][nt(8)][ks(32)][nr(128)][kl(32)]
__global__ __launch_bounds__(256) void k_adj(const int* __restrict__ conn, unsigned short* __restrict__ Abf) {
  const int idx = blockIdx.x * 256 + threadIdx.x;      // 1,048,576 int4s
  int4 c = ((const int4*)conn)[idx];
  ushort4 o;
  o.x = f2bf((float)c.x); o.y = f2bf((float)c.y);
  o.z = f2bf((float)c.z); o.w = f2bf((float)c.w);
  const int b   = idx >> 18;          // 262144 int4 per batch
  const int rem = idx & 262143;
  const int n   = rem >> 8;           // 256 int4 per n-row
  const int mq  = rem & 255;
  const int nt = n >> 7, nr = n & 127;
  const int ks = mq >> 3, kl = (mq & 7) * 4;
  *(ushort4*)&Abf[(size_t)(b * 8 + nt) * 131072 + ks * 4096 + nr * 32 + kl] = o;
}

// K3: CG products -> PtT[b][ft(26)][ks(32)][fr(128)][kl(32)] (bf16, f padded to 3328)
#define VSTRIDE 148   // floats per m-row: 144 data + 4 pad (16B-aligned, odd/4 bank step)

template <int L>
__device__ __forceinline__ void cg_emit(const float* __restrict__ vme, const float sxr[9],
                                        const float* __restrict__ cgt,
                                        unsigned short* __restrict__ pout, int cbase) {
  const int nfrag = (L == 0) ? 3 : 6;
  const int nk = 2 * L + 1;
  const int Lbase = (L == 0) ? 0 : (L == 1 ? 192 : 1344);
  const int Cfrag = nfrag * 64;
#pragma unroll
  for (int frag = 0; frag < nfrag; ++frag) {
    const int l1 = d_l1[L][frag], l2 = d_l2[L][frag];
    const int n1 = 2 * l1 + 1, n2 = 2 * l2 + 1;
    const int rb1 = d_rb[l1], rb2 = d_rb[l2];
    const int cgo = d_off[L][frag];
#pragma unroll
    for (int k = 0; k < nk; ++k) {
      float w[5];
#pragma unroll
      for (int i = 0; i < n1; ++i) {
        float a = 0.f;
#pragma unroll
        for (int j = 0; j < n2; ++j)
          a += sxr[rb2 + j] * cgt[cgo + (i * n2 + j) * nk + k];  // uniform idx -> s_load
        w[i] = a;
      }
      f32x4 val = {0.f, 0.f, 0.f, 0.f};
#pragma unroll
      for (int i = 0; i < n1; ++i) {
        f32x4 vv = *(const f32x4*)(vme + (rb1 + i) * 16);       // ds_read_b128
        val += vv * w[i];
      }
      const int fb = Lbase + k * Cfrag + frag * 64 + cbase;     // fb..fb+3 in one 128-tile
      const int ftile = fb >> 7, fr = fb & 127;
#pragma unroll
      for (int cc = 0; cc < 4; ++cc)
        pout[(size_t)ftile * 131072 + (size_t)(fr + cc) * 32] = f2bf(val[cc]);
    }
  }
}

__global__ __launch_bounds__(256) void k_cgp(const float* __restrict__ v0, const float* __restrict__ v1,
                                             const float* __restrict__ v2, const float* __restrict__ sx,
                                             const float* __restrict__ cgt, unsigned short* __restrict__ Pt) {
  __shared__ float vsh[64 * VSTRIDE];   // [m][r*16 + cLocal], r=0..8 stacked rows, 16 c per block
  const int half = blockIdx.x & 1;
  const int cq   = blockIdx.x >> 1;     // 0..3
  const int mt   = blockIdx.y;          // 0..15
  const int b    = blockIdx.z;
  const int m0 = mt * 64;
  const int c0 = cq * 16;
  const int tid = threadIdx.x;
  const size_t nb = (size_t)b * N_ + m0;

  // load + transpose v tile: 64 m x 9 rows x 16 c
  for (int e = tid; e < 9216; e += 256) {
    const int m = e / 144, rest = e % 144;
    const int r = rest >> 4, cc = rest & 15;
    float val;
    if (r == 0)      val = v0[(nb + m) * 64 + c0 + cc];
    else if (r < 4)  val = v1[((nb + m) * 3 + (r - 1)) * 64 + c0 + cc];
    else             val = v2[((nb + m) * 5 + (r - 4)) * 64 + c0 + cc];
    vsh[m * VSTRIDE + rest] = val;
  }
  const int lane = tid & 63, wv = tid >> 6;
  float sxr[9];
#pragma unroll
  for (int r = 0; r < 9; ++r) sxr[r] = sx[(nb + lane) * 9 + r];
  __syncthreads();

  const int ks = mt * 2 + (lane >> 5);          // global k-step of this lane's m
  unsigned short* pout = Pt + (size_t)b * 26 * 131072 + ks * 4096 + (lane & 31);
  const int cbase = c0 + wv * 4;
  const float* vme = &vsh[lane * VSTRIDE + wv * 4];

  if (half == 0) {
    cg_emit<0>(vme, sxr, cgt, pout, cbase);
    cg_emit<1>(vme, sxr, cgt, pout, cbase);
  } else {
    cg_emit<2>(vme, sxr, cgt, pout, cbase);
    // zero the pad rows f in [3264, 3328): ftile 25, fr = 64+cbase+cc
#pragma unroll
    for (int cc = 0; cc < 4; ++cc)
      pout[(size_t)25 * 131072 + (size_t)(64 + cbase + cc) * 32] = 0;
  }
}

// K4: mp[b][n][f] = sum_m PtT*AbT; operands pre-tiled so every K-step reads one
// contiguous 8KB chunk per operand (gload16 = 1KB contiguous, sequential over ks).
__global__ __launch_bounds__(256) void k_gemm(const unsigned short* __restrict__ PtT,
                                              const unsigned short* __restrict__ AbT,
                                              float* __restrict__ out, float* __restrict__ ssv) {
  __shared__ unsigned short As[4096];
  __shared__ unsigned short Bs[4096];
  // XCD-rectangle swizzle: each XCD (blk%8) gets a 13ft x 2nt rectangle (~3.9MB in L2)
  const int i  = blockIdx.x;          // 0..831
  const int x  = i & 7, j = i >> 3;   // x: XCD bucket, j: 0..103
  const int b  = j / 26;
  const int r  = j % 26;
  const int ft = (x >> 2) * 13 + (r % 13);
  const int nt = (x & 3) * 2 + (r / 13);
  const int f0 = ft * 128, n0 = nt * 128;
  const int tid  = threadIdx.x;
  const int wid  = tid >> 6, lane = tid & 63;
  const int wr   = wid >> 1, wc = wid & 1;
  const int l16  = lane & 15, quad = lane >> 4;

  const unsigned short* pA = PtT + (size_t)(b * 26 + ft) * 131072;
  const unsigned short* pB = AbT + (size_t)(b * 8  + nt) * 131072;
  const unsigned short* gA = pA + wid * 1024 + lane * 8;
  const unsigned short* gB = pB + wid * 1024 + lane * 8;
  unsigned short* lA = &As[wid * 1024];
  unsigned short* lB = &Bs[wid * 1024];

  f32x4 acc[4][4] = {};

  for (int ks = 0; ks < 32; ++ks) {
    const int off = ks * 4096;
    gload16(gA + off,       lA);
    gload16(gA + off + 512, lA + 512);
    gload16(gB + off,       lB);
    gload16(gB + off + 512, lB + 512);
    __syncthreads();
    short8 af[4], bf[4];
#pragma unroll
    for (int mi = 0; mi < 4; ++mi)
      af[mi] = *(const short8*)&As[(wr*64 + mi*16 + l16)*32 + quad*8];
#pragma unroll
    for (int ni = 0; ni < 4; ++ni)
      bf[ni] = *(const short8*)&Bs[(wc*64 + ni*16 + l16)*32 + quad*8];
#pragma unroll
    for (int mi = 0; mi < 4; ++mi)
#pragma unroll
      for (int ni = 0; ni < 4; ++ni)
        acc[mi][ni] = __builtin_amdgcn_mfma_f32_16x16x32_bf16(af[mi], bf[ni], acc[mi][ni], 0, 0, 0);
    __syncthreads();
  }

  // epilogue: D[row=f_local][col=n_local], row = quad*4+reg, col = lane&15 (m89-verified)
  float ssl0 = 0.f, ssl1 = 0.f, ssl2 = 0.f;
#pragma unroll
  for (int mi = 0; mi < 4; ++mi) {
    const int fbase = f0 + wr*64 + mi*16 + quad*4;   // L boundaries (192,1344,3264) are 16-aligned
    if (fbase >= FTOT) continue;
    float sq = 0.f;
#pragma unroll
    for (int ni = 0; ni < 4; ++ni) {
      const int n = n0 + wc*64 + ni*16 + l16;
      f32x4 v = acc[mi][ni];
      sq += v[0]*v[0] + v[1]*v[1] + v[2]*v[2] + v[3]*v[3];
      *(f32x4*)&out[((size_t)b * N_ + n) * FTOT + fbase] = v;
    }
    if (fbase < 192) ssl0 += sq; else if (fbase < 1344) ssl1 += sq; else ssl2 += sq;
  }
  ssl0 = wave_sum(ssl0); ssl1 = wave_sum(ssl1); ssl2 = wave_sum(ssl2);
  if (lane == 0) {
    if (ssl0 != 0.f) atomicAdd(&ssv[0], ssl0);
    if (ssl1 != 0.f) atomicAdd(&ssv[1], ssl1);
    if (ssl2 != 0.f) atomicAdd(&ssv[2], ssl2);
  }
}

// K5: in-place scale by 64 / ((2L+1)*||mp_L||_F)
__global__ __launch_bounds__(256) void k_scale(float* __restrict__ out, const float* __restrict__ ssv) {
  const int idx = blockIdx.x * 256 + threadIdx.x;   // float4 index
  const int total = B_ * N_ * (FTOT / 4);
  if (idx >= total) return;
  const int f = (idx % (FTOT / 4)) * 4;
  const int L = f < 192 ? 0 : (f < 1344 ? 1 : 2);
  const float sc = 64.f / ((float)(2*L+1) * sqrtf(ssv[L]));
  f32x4* p = (f32x4*)out + idx;
  f32x4 v = *p;
  v *= sc;
  *p = v;
}

extern "C" void kernel_launch(void* const* d_in, const int* in_sizes, int n_in,
                              void* d_out, int out_size, void* d_ws, size_t ws_size,
                              hipStream_t stream) {
  const float* v0 = (const float*)d_in[0];
  const float* v1 = (const float*)d_in[1];
  const float* v2 = (const float*)d_in[2];
  const float* s0 = (const float*)d_in[3];
  const float* s1 = (const float*)d_in[4];
  const float* s2 = (const float*)d_in[5];
  const int* conn = (const int*)d_in[6];
  char* ws = (char*)d_ws;
  float* ss            = (float*)(ws + WS_SS);
  float* cg            = (float*)(ws + WS_CG);
  float* sx            = (float*)(ws + WS_SX);
  unsigned short* Abf  = (unsigned short*)(ws + WS_ABF);
  unsigned short* Pt   = (unsigned short*)(ws + WS_PT);
  float* out = (float*)d_out;

  k_init <<<dim3(1),            dim3(640), 0, stream>>>(ss, cg);
  k_sx   <<<dim3(B_ * N_),      dim3(256), 0, stream>>>(s0, s1, s2, sx);
  k_adj  <<<dim3(4096),         dim3(256), 0, stream>>>(conn, Abf);
  k_cgp  <<<dim3(8, 16, B_),    dim3(256), 0, stream>>>(v0, v1, v2, sx, cg, Pt);
  k_gemm <<<dim3(832),          dim3(256), 0, stream>>>(Pt, Abf, out, ss);
  k_scale<<<dim3(13056),        dim3(256), 0, stream>>>(out, ss);
}

// Round 4
// 329.034 us; speedup vs baseline: 1.3237x; 1.0427x over previous
//
#include <hip/hip_runtime.h>
#include <math.h>

typedef __attribute__((ext_vector_type(8))) short short8;
typedef __attribute__((ext_vector_type(4))) float f32x4;

#define B_   4
#define N_   1024
#define FTOT 3264
#define FPAD 3328

// workspace offsets (bytes)
#define WS_SS   0
#define WS_CG   256
#define WS_SX   4096
#define WS_ABF  151552
#define WS_PT   8540160
// total ws use: 35,803,136 bytes

__device__ __forceinline__ unsigned short f2bf(float x) {
  union { float f; unsigned u; } v; v.f = x;
  unsigned r = v.u + 0x7FFFu + ((v.u >> 16) & 1u);
  return (unsigned short)(r >> 16);
}

__device__ __forceinline__ void gload16(const void* gp, void* lp) {
  __builtin_amdgcn_global_load_lds((const __attribute__((address_space(1))) unsigned int*)gp,
                                   (__attribute__((address_space(3))) unsigned int*)lp, 16, 0, 0);
}

__device__ __forceinline__ float wave_sum(float v) {
#pragma unroll
  for (int off = 32; off > 0; off >>= 1) v += __shfl_down(v, off, 64);
  return v;
}

// ---------------- CG coefficient machinery ----------------
__device__ double dfact(int n) { double r = 1.0; for (int i = 2; i <= n; ++i) r *= (double)i; return r; }

__device__ float cg_coeff(int l1, int m1, int l2, int m2, int L, int M) {
  if (m1 + m2 != M) return 0.f;
  int dl = l1 - l2; if (dl < 0) dl = -dl;
  if (L < dl || L > l1 + l2) return 0.f;
  double pre = sqrt((double)(2*L+1) * dfact(L+l1-l2) * dfact(L-l1+l2) * dfact(l1+l2-L) / dfact(l1+l2+L+1));
  pre *= sqrt(dfact(L+M)*dfact(L-M)*dfact(l1-m1)*dfact(l1+m1)*dfact(l2-m2)*dfact(l2+m2));
  double s = 0.0;
  for (int k = 0; k <= l1 + l2 - L; ++k) {
    int d1 = l1+l2-L-k, d2 = l1-m1-k, d3 = l2+m2-k, d4 = L-l2+m1+k, d5 = L-l1-m2+k;
    if (d1 < 0 || d2 < 0 || d3 < 0 || d4 < 0 || d5 < 0) continue;
    double t = (k & 1) ? -1.0 : 1.0;
    t /= dfact(k)*dfact(d1)*dfact(d2)*dfact(d3)*dfact(d4)*dfact(d5);
    s += t;
  }
  return (float)(pre * s);
}

// 15 CG tables in (L, frag) order; dense [i][j][k] layout, offsets below.
__device__ const int t_l1[15]  = {0,1,2, 0,1,1,1,2,2, 0,1,1,2,2,2};
__device__ const int t_l2[15]  = {0,1,2, 1,0,1,2,1,2, 2,1,2,0,1,2};
__device__ const int t_L [15]  = {0,0,0, 1,1,1,1,1,1, 2,2,2,2,2,2};
__device__ const int t_off[16] = {0,1,10, 35,44,53,80,125,170, 245,270,315,390,415,490, 615};

// per-L frag decode tables (frag order = reference's (l1,l2) loop order)
__device__ const int d_l1[3][6]  = {{0,1,2,0,0,0},{0,1,1,1,2,2},{0,1,1,2,2,2}};
__device__ const int d_l2[3][6]  = {{0,1,2,0,0,0},{1,0,1,2,1,2},{2,1,2,0,1,2}};
__device__ const int d_off[3][6] = {{0,1,10,0,0,0},{35,44,53,80,125,170},{245,270,315,390,415,490}};
__device__ const int d_rb[3] = {0, 1, 4};   // row base of degree l in the 9-row (m) stack

// Chunk layout (4096 shorts = [128 rows][32 k]) is FRAGMENT-MAJOR:
//   flat(row,k) = ((row>>4)*4 + (k>>3))*128 + (row&15)*8 + (k&7)
// so an MFMA fragment read (16 rows x 8 k for fixed quad) is lane-linear 1KB
// in LDS -> conflict-free ds_read_b128.

// K0: zero sumsq accumulators + build CG table (runs every launch; graph-safe)
__global__ void k_init(float* ss, float* cg) {
  int tid = threadIdx.x;
  if (tid < 4) ss[tid] = 0.f;
  if (tid >= 615) return;
  int t = 0;
  while (t < 14 && tid >= t_off[t+1]) ++t;
  int local = tid - t_off[t];
  int l1 = t_l1[t], l2 = t_l2[t], L = t_L[t];
  int nk = 2*L+1, n2 = 2*l2+1;
  int k = local % nk; int rest = local / nk;
  int j = rest % n2;  int i = rest / n2;
  cg[tid] = cg_coeff(l1, i - l1, l2, j - l2, L, k - L);
}

// K1: sx[b,n,r] = sum_j s_l[b,n,j,m]  (r = stacked 9 m-rows)
__global__ __launch_bounds__(256) void k_sx(const float* __restrict__ s0p, const float* __restrict__ s1p,
                                            const float* __restrict__ s2p, float* __restrict__ sx) {
  __shared__ float red[9][256];
  const int bn = blockIdx.x;
  const int tid = threadIdx.x;
  const float* p0 = s0p + (size_t)bn * 1024;
  const float* p1 = s1p + (size_t)bn * 3072;
  const float* p2 = s2p + (size_t)bn * 5120;
  float a0 = 0.f;
  for (int i = tid; i < 1024; i += 256) a0 += p0[i];
  float b0 = 0.f, b1 = 0.f, b2 = 0.f;
  for (int i = tid; i < 3072; i += 768) { b0 += p1[i]; b1 += p1[i+256]; b2 += p1[i+512]; }
  float c0=0.f,c1=0.f,c2=0.f,c3=0.f,c4=0.f;
  for (int i = tid; i < 5120; i += 1280) {
    c0 += p2[i]; c1 += p2[i+256]; c2 += p2[i+512]; c3 += p2[i+768]; c4 += p2[i+1024];
  }
  red[0][tid] = a0;
  const int r3 = tid % 3;              // flat idx % 3 == m  (256 ≡ 1 mod 3)
  red[1 + r3][tid]        = b0;
  red[1 + (r3+1)%3][tid]  = b1;
  red[1 + (r3+2)%3][tid]  = b2;
  const int r5 = tid % 5;              // 256 ≡ 1 mod 5
  red[4 + r5][tid]        = c0;
  red[4 + (r5+1)%5][tid]  = c1;
  red[4 + (r5+2)%5][tid]  = c2;
  red[4 + (r5+3)%5][tid]  = c3;
  red[4 + (r5+4)%5][tid]  = c4;
  __syncthreads();
  for (int s = 128; s > 0; s >>= 1) {
    if (tid < s) {
#pragma unroll
      for (int r = 0; r < 9; ++r) red[r][tid] += red[r][tid + s];
    }
    __syncthreads();
  }
  if (tid < 9) sx[(size_t)bn * 9 + tid] = red[tid][0];
}

// K2: adjacency int32 -> bf16 in fragment-major tiled layout.
// Each thread handles 8 consecutive m; wave = 16 n x 4 k-octets -> ushort8
// stores cover a contiguous 1KB block.
__global__ __launch_bounds__(256) void k_adj(const int* __restrict__ conn, unsigned short* __restrict__ Abf) {
  const int idx  = blockIdx.x * 256 + threadIdx.x;   // 0..524287
  const int lane = idx & 63;
  const int w    = (idx >> 6) & 2047;                // wave within batch
  const int b    = idx >> 17;
  const int nt16 = w >> 5;                           // 16-row n tile (0..63)
  const int ks   = w & 31;
  const int l16  = lane & 15, quad = lane >> 4;
  const int n    = nt16 * 16 + l16;
  const int m8   = ks * 32 + quad * 8;
  const int4* src = (const int4*)(conn + ((size_t)(b * 1024 + n) * 1024 + m8));
  int4 c0 = src[0], c1 = src[1];
  short8 o;
  o[0] = f2bf((float)c0.x); o[1] = f2bf((float)c0.y);
  o[2] = f2bf((float)c0.z); o[3] = f2bf((float)c0.w);
  o[4] = f2bf((float)c1.x); o[5] = f2bf((float)c1.y);
  o[6] = f2bf((float)c1.z); o[7] = f2bf((float)c1.w);
  const int nt = n >> 7, nr = n & 127;
  *(short8*)&Abf[(size_t)(b * 8 + nt) * 131072 + ks * 4096 +
                 ((nr >> 4) * 4 + quad) * 128 + (nr & 15) * 8] = o;
}

// K3: CG products -> PtT[b][ft(26)][ks(32)][fragment-major chunk] (bf16, padded to 3328)
#define VSTRIDE 148   // floats per m-row: 144 data + 4 pad (16B-aligned, odd/4 bank step)

template <int L>
__device__ __forceinline__ void cg_emit(const float* __restrict__ vme, const float sxr[9],
                                        const float* __restrict__ cgt,
                                        unsigned short* __restrict__ pout, int cbase) {
  const int nfrag = (L == 0) ? 3 : 6;
  const int nk = 2 * L + 1;
  const int Lbase = (L == 0) ? 0 : (L == 1 ? 192 : 1344);
  const int Cfrag = nfrag * 64;
#pragma unroll
  for (int frag = 0; frag < nfrag; ++frag) {
    const int l1 = d_l1[L][frag], l2 = d_l2[L][frag];
    const int n1 = 2 * l1 + 1, n2 = 2 * l2 + 1;
    const int rb1 = d_rb[l1], rb2 = d_rb[l2];
    const int cgo = d_off[L][frag];
#pragma unroll
    for (int k = 0; k < nk; ++k) {
      float w[5];
#pragma unroll
      for (int i = 0; i < n1; ++i) {
        float a = 0.f;
#pragma unroll
        for (int j = 0; j < n2; ++j)
          a += sxr[rb2 + j] * cgt[cgo + (i * n2 + j) * nk + k];  // uniform idx -> s_load
        w[i] = a;
      }
      f32x4 val = {0.f, 0.f, 0.f, 0.f};
#pragma unroll
      for (int i = 0; i < n1; ++i) {
        f32x4 vv = *(const f32x4*)(vme + (rb1 + i) * 16);       // ds_read_b128
        val += vv * w[i];
      }
      const int fb = Lbase + k * Cfrag + frag * 64 + cbase;     // 4-aligned, fb..fb+3 same 16-row
      const int ftile = fb >> 7, fr = fb & 127;
      unsigned short* pp = pout + (size_t)ftile * 131072 + (fr >> 4) * 512 + (fr & 15) * 8;
#pragma unroll
      for (int cc = 0; cc < 4; ++cc)
        pp[cc * 8] = f2bf(val[cc]);
    }
  }
}

__global__ __launch_bounds__(256) void k_cgp(const float* __restrict__ v0, const float* __restrict__ v1,
                                             const float* __restrict__ v2, const float* __restrict__ sx,
                                             const float* __restrict__ cgt, unsigned short* __restrict__ Pt) {
  __shared__ float vsh[64 * VSTRIDE];   // [m][r*16 + cLocal], r=0..8 stacked rows, 16 c per block
  const int half = blockIdx.x & 1;
  const int cq   = blockIdx.x >> 1;     // 0..3
  const int mt   = blockIdx.y;          // 0..15
  const int b    = blockIdx.z;
  const int m0 = mt * 64;
  const int c0 = cq * 16;
  const int tid = threadIdx.x;
  const size_t nb = (size_t)b * N_ + m0;

  // load + transpose v tile: 64 m x 9 rows x 16 c
  for (int e = tid; e < 9216; e += 256) {
    const int m = e / 144, rest = e % 144;
    const int r = rest >> 4, cc = rest & 15;
    float val;
    if (r == 0)      val = v0[(nb + m) * 64 + c0 + cc];
    else if (r < 4)  val = v1[((nb + m) * 3 + (r - 1)) * 64 + c0 + cc];
    else             val = v2[((nb + m) * 5 + (r - 4)) * 64 + c0 + cc];
    vsh[m * VSTRIDE + rest] = val;
  }
  const int lane = tid & 63, wv = tid >> 6;
  float sxr[9];
#pragma unroll
  for (int r = 0; r < 9; ++r) sxr[r] = sx[(nb + lane) * 9 + r];
  __syncthreads();

  const int ks = mt * 2 + (lane >> 5);          // global k-step of this lane's m
  const int kq = ((lane & 31) >> 3) * 128 + (lane & 7);   // fragment-major k offset
  unsigned short* pout = Pt + (size_t)b * 26 * 131072 + ks * 4096 + kq;
  const int cbase = c0 + wv * 4;
  const float* vme = &vsh[lane * VSTRIDE + wv * 4];

  if (half == 0) {
    cg_emit<0>(vme, sxr, cgt, pout, cbase);
    cg_emit<1>(vme, sxr, cgt, pout, cbase);
  } else {
    cg_emit<2>(vme, sxr, cgt, pout, cbase);
    // zero the pad rows f in [3264, 3328): ftile 25, fr = 64+cbase+cc
    const int fr = 64 + cbase;
    unsigned short* pp = pout + (size_t)25 * 131072 + (fr >> 4) * 512 + (fr & 15) * 8;
#pragma unroll
    for (int cc = 0; cc < 4; ++cc)
      pp[cc * 8] = 0;
  }
}

// K4: mp[b][n][f] = sum_m PtT*AbT. Double-buffered BK=64 pipeline:
// stage s+1 always in flight (s_waitcnt vmcnt(8), never 0 until tail),
// raw s_barrier, fragment-major LDS -> conflict-free ds_read_b128.
#define WAIT_VM8 0x0F78   // vmcnt=8, expcnt=7 (nowait), lgkmcnt=15 (nowait)
#define WAIT_VM0 0x0F70   // vmcnt=0

__global__ __launch_bounds__(256) void k_gemm(const unsigned short* __restrict__ PtT,
                                              const unsigned short* __restrict__ AbT,
                                              float* __restrict__ out, float* __restrict__ ssv) {
  __shared__ unsigned short As[2][8192];
  __shared__ unsigned short Bs[2][8192];
  // XCD-rectangle swizzle: each XCD (blk%8) gets a 13ft x 2nt rectangle (~3.9MB in L2)
  const int i  = blockIdx.x;          // 0..831
  const int x  = i & 7, j = i >> 3;   // x: XCD bucket, j: 0..103
  const int b  = j / 26;
  const int r  = j % 26;
  const int ft = (x >> 2) * 13 + (r % 13);
  const int nt = (x & 3) * 2 + (r / 13);
  const int f0 = ft * 128, n0 = nt * 128;
  const int tid  = threadIdx.x;
  const int wid  = tid >> 6, lane = tid & 63;
  const int wr   = wid >> 1, wc = wid & 1;
  const int l16  = lane & 15, quad = lane >> 4;

  const unsigned short* gA = PtT + (size_t)(b * 26 + ft) * 131072 + wid * 2048 + lane * 8;
  const unsigned short* gB = AbT + (size_t)(b * 8  + nt) * 131072 + wid * 2048 + lane * 8;

#define ISSUE(S, BUF) do { \
    const unsigned short* a_ = gA + (S) * 8192; \
    const unsigned short* b_ = gB + (S) * 8192; \
    unsigned short* la_ = &As[BUF][wid * 2048]; \
    unsigned short* lb_ = &Bs[BUF][wid * 2048]; \
    gload16(a_,        la_);        gload16(a_ +  512, la_ +  512); \
    gload16(a_ + 1024, la_ + 1024); gload16(a_ + 1536, la_ + 1536); \
    gload16(b_,        lb_);        gload16(b_ +  512, lb_ +  512); \
    gload16(b_ + 1024, lb_ + 1024); gload16(b_ + 1536, lb_ + 1536); \
  } while (0)

  f32x4 acc[4][4] = {};

#define COMPUTE(BUF) do { \
    _Pragma("unroll") \
    for (int kc = 0; kc < 2; ++kc) { \
      short8 af[4], bf[4]; \
      _Pragma("unroll") \
      for (int mi = 0; mi < 4; ++mi) \
        af[mi] = *(const short8*)&As[BUF][kc*4096 + (wr*4+mi)*512 + quad*128 + l16*8]; \
      _Pragma("unroll") \
      for (int ni = 0; ni < 4; ++ni) \
        bf[ni] = *(const short8*)&Bs[BUF][kc*4096 + (wc*4+ni)*512 + quad*128 + l16*8]; \
      _Pragma("unroll") \
      for (int mi = 0; mi < 4; ++mi) \
        _Pragma("unroll") \
        for (int ni = 0; ni < 4; ++ni) \
          acc[mi][ni] = __builtin_amdgcn_mfma_f32_16x16x32_bf16(af[mi], bf[ni], acc[mi][ni], 0, 0, 0); \
    } \
  } while (0)

  ISSUE(0, 0);
  ISSUE(1, 1);
  for (int s = 0; s < 15; ++s) {
    const int buf = s & 1;
    __builtin_amdgcn_s_waitcnt(WAIT_VM8);   // stage s landed; stage s+1 stays in flight
    __builtin_amdgcn_s_barrier();
    COMPUTE(buf);
    __builtin_amdgcn_s_barrier();           // all waves done reading buf
    if (s < 14) ISSUE(s + 2, buf);
  }
  __builtin_amdgcn_s_waitcnt(WAIT_VM0);     // tail: stage 15
  __builtin_amdgcn_s_barrier();
  COMPUTE(1);

  // epilogue: D[row=f_local][col=n_local], row = quad*4+reg, col = lane&15 (m89-verified)
  float ssl0 = 0.f, ssl1 = 0.f, ssl2 = 0.f;
#pragma unroll
  for (int mi = 0; mi < 4; ++mi) {
    const int fbase = f0 + wr*64 + mi*16 + quad*4;   // L boundaries (192,1344,3264) are 16-aligned
    if (fbase >= FTOT) continue;
    float sq = 0.f;
#pragma unroll
    for (int ni = 0; ni < 4; ++ni) {
      const int n = n0 + wc*64 + ni*16 + l16;
      f32x4 v = acc[mi][ni];
      sq += v[0]*v[0] + v[1]*v[1] + v[2]*v[2] + v[3]*v[3];
      *(f32x4*)&out[((size_t)b * N_ + n) * FTOT + fbase] = v;
    }
    if (fbase < 192) ssl0 += sq; else if (fbase < 1344) ssl1 += sq; else ssl2 += sq;
  }
  ssl0 = wave_sum(ssl0); ssl1 = wave_sum(ssl1); ssl2 = wave_sum(ssl2);
  if (lane == 0) {
    if (ssl0 != 0.f) atomicAdd(&ssv[0], ssl0);
    if (ssl1 != 0.f) atomicAdd(&ssv[1], ssl1);
    if (ssl2 != 0.f) atomicAdd(&ssv[2], ssl2);
  }
#undef ISSUE
#undef COMPUTE
}

// K5: in-place scale by 64 / ((2L+1)*||mp_L||_F)
__global__ __launch_bounds__(256) void k_scale(float* __restrict__ out, const float* __restrict__ ssv) {
  const int idx = blockIdx.x * 256 + threadIdx.x;   // float4 index
  const int total = B_ * N_ * (FTOT / 4);
  if (idx >= total) return;
  const int f = (idx % (FTOT / 4)) * 4;
  const int L = f < 192 ? 0 : (f < 1344 ? 1 : 2);
  const float sc = 64.f / ((float)(2*L+1) * sqrtf(ssv[L]));
  f32x4* p = (f32x4*)out + idx;
  f32x4 v = *p;
  v *= sc;
  *p = v;
}

extern "C" void kernel_launch(void* const* d_in, const int* in_sizes, int n_in,
                              void* d_out, int out_size, void* d_ws, size_t ws_size,
                              hipStream_t stream) {
  const float* v0 = (const float*)d_in[0];
  const float* v1 = (const float*)d_in[1];
  const float* v2 = (const float*)d_in[2];
  const float* s0 = (const float*)d_in[3];
  const float* s1 = (const float*)d_in[4];
  const float* s2 = (const float*)d_in[5];
  const int* conn = (const int*)d_in[6];
  char* ws = (char*)d_ws;
  float* ss            = (float*)(ws + WS_SS);
  float* cg            = (float*)(ws + WS_CG);
  float* sx            = (float*)(ws + WS_SX);
  unsigned short* Abf  = (unsigned short*)(ws + WS_ABF);
  unsigned short* Pt   = (unsigned short*)(ws + WS_PT);
  float* out = (float*)d_out;

  k_init <<<dim3(1),            dim3(640), 0, stream>>>(ss, cg);
  k_sx   <<<dim3(B_ * N_),      dim3(256), 0, stream>>>(s0, s1, s2, sx);
  k_adj  <<<dim3(2048),         dim3(256), 0, stream>>>(conn, Abf);
  k_cgp  <<<dim3(8, 16, B_),    dim3(256), 0, stream>>>(v0, v1, v2, sx, cg, Pt);
  k_gemm <<<dim3(832),          dim3(256), 0, stream>>>(Pt, Abf, out, ss);
  k_scale<<<dim3(13056),        dim3(256), 0, stream>>>(out, ss);
}